// Round 5
// baseline (103.283 us; speedup 1.0000x reference)
//
#include <hip/hip_runtime.h>

// NeighborList: N atoms, minimum-image convention, cutoff 5.0.
// Output layout (all float32): pairs[2*P], deltas[P*3], distances[P], n_pairs[1]
// Ordering must match jnp.nonzero(mask.ravel()) -> ascending flat index i*N+j.
//
// Two dispatches (cooperative grid.sync measured 100+us on this chip -- avoid):
//  K1: pad output + LDS-staged per-row count + per-chunk 64-bit hit masks
//      (row-paired waves (w, N-1-w) for deterministic balance; positions
//      staged once per block in LDS -> inner loop is ds_read, not L2).
//  K2: per-wave inline exclusive prefix over counts[] + ordered fill from masks.

#define CUT2 25.0f

__device__ __forceinline__ void load_box_inv(const float* __restrict__ box,
                                             float B[3][3], float Binv[3][3]) {
    #pragma unroll
    for (int r = 0; r < 3; ++r)
        #pragma unroll
        for (int c = 0; c < 3; ++c)
            B[r][c] = box[r * 3 + c];

    float a00 = B[0][0], a01 = B[0][1], a02 = B[0][2];
    float a10 = B[1][0], a11 = B[1][1], a12 = B[1][2];
    float a20 = B[2][0], a21 = B[2][1], a22 = B[2][2];

    float adj00 =  (a11 * a22 - a12 * a21);
    float adj01 = -(a01 * a22 - a02 * a21);
    float adj02 =  (a01 * a12 - a02 * a11);
    float adj10 = -(a10 * a22 - a12 * a20);
    float adj11 =  (a00 * a22 - a02 * a20);
    float adj12 = -(a00 * a12 - a02 * a10);
    float adj20 =  (a10 * a21 - a11 * a20);
    float adj21 = -(a00 * a21 - a01 * a20);
    float adj22 =  (a00 * a11 - a01 * a10);

    float det = a00 * adj00 + a01 * adj10 + a02 * adj20;

    // per-entry division: for diagonal box this rounds identically to
    // LAPACK's 1/pivot (single rounding of the exact quotient).
    Binv[0][0] = __fdiv_rn(adj00, det); Binv[0][1] = __fdiv_rn(adj01, det); Binv[0][2] = __fdiv_rn(adj02, det);
    Binv[1][0] = __fdiv_rn(adj10, det); Binv[1][1] = __fdiv_rn(adj11, det); Binv[1][2] = __fdiv_rn(adj12, det);
    Binv[2][0] = __fdiv_rn(adj20, det); Binv[2][1] = __fdiv_rn(adj21, det); Binv[2][2] = __fdiv_rn(adj22, det);
}

// Replicates numpy rounding exactly (no FMA contraction):
// delta = pos_i - pos_j; frac = delta @ Binv; delta -= rint(frac) @ B; d2 = sum(delta^2)
__device__ __forceinline__ void min_image(float xi, float yi, float zi,
                                          float xj, float yj, float zj,
                                          const float B[3][3], const float Binv[3][3],
                                          float& dx, float& dy, float& dz, float& d2) {
    dx = __fsub_rn(xi, xj);
    dy = __fsub_rn(yi, yj);
    dz = __fsub_rn(zi, zj);

    float f0 = __fadd_rn(__fadd_rn(__fmul_rn(dx, Binv[0][0]), __fmul_rn(dy, Binv[1][0])), __fmul_rn(dz, Binv[2][0]));
    float f1 = __fadd_rn(__fadd_rn(__fmul_rn(dx, Binv[0][1]), __fmul_rn(dy, Binv[1][1])), __fmul_rn(dz, Binv[2][1]));
    float f2 = __fadd_rn(__fadd_rn(__fmul_rn(dx, Binv[0][2]), __fmul_rn(dy, Binv[1][2])), __fmul_rn(dz, Binv[2][2]));

    float r0 = rintf(f0), r1 = rintf(f1), r2 = rintf(f2);

    float c0 = __fadd_rn(__fadd_rn(__fmul_rn(r0, B[0][0]), __fmul_rn(r1, B[1][0])), __fmul_rn(r2, B[2][0]));
    float c1 = __fadd_rn(__fadd_rn(__fmul_rn(r0, B[0][1]), __fmul_rn(r1, B[1][1])), __fmul_rn(r2, B[2][1]));
    float c2 = __fadd_rn(__fadd_rn(__fmul_rn(r0, B[0][2]), __fmul_rn(r1, B[1][2])), __fmul_rn(r2, B[2][2]));

    dx = __fsub_rn(dx, c0);
    dy = __fsub_rn(dy, c1);
    dz = __fsub_rn(dz, c2);

    d2 = __fadd_rn(__fadd_rn(__fmul_rn(dx, dx), __fmul_rn(dy, dy)), __fmul_rn(dz, dz));
}

// Count hits for row i (j > i) reading positions from LDS; write per-chunk
// 64-bit masks to mrow[]. Inner loop unrolled x4 for ILP.
__device__ __forceinline__ int count_row_lds(int i, int lane,
                                             const float* __restrict__ spos,
                                             const float B[3][3], const float Binv[3][3],
                                             unsigned long long* __restrict__ mrow,
                                             int nchunks) {
    float xi = spos[3 * i + 0], yi = spos[3 * i + 1], zi = spos[3 * i + 2];
    int c0 = i >> 6;
    int cnt = 0;

    // Diagonal chunk: needs the j>i predicate.
    {
        int j = (c0 << 6) + lane;
        bool hit = false;
        if (j > i) {
            float dx, dy, dz, d2;
            min_image(xi, yi, zi, spos[3 * j + 0], spos[3 * j + 1], spos[3 * j + 2],
                      B, Binv, dx, dy, dz, d2);
            hit = (d2 < CUT2);
        }
        unsigned long long m = __ballot(hit);
        if (lane == 0) mrow[c0] = m;
        cnt += __popcll(m);
    }

    // Remaining chunks: all j > i. Unroll x4.
    int c = c0 + 1;
    for (; c + 4 <= nchunks; c += 4) {
        int j0 = (c << 6) + lane;
        float dx0, dy0, dz0, d20, dx1, dy1, dz1, d21;
        float dx2, dy2, dz2, d22, dx3, dy3, dz3, d23;
        min_image(xi, yi, zi, spos[3 * j0 + 0],   spos[3 * j0 + 1],   spos[3 * j0 + 2],   B, Binv, dx0, dy0, dz0, d20);
        min_image(xi, yi, zi, spos[3 * j0 + 192], spos[3 * j0 + 193], spos[3 * j0 + 194], B, Binv, dx1, dy1, dz1, d21);
        min_image(xi, yi, zi, spos[3 * j0 + 384], spos[3 * j0 + 385], spos[3 * j0 + 386], B, Binv, dx2, dy2, dz2, d22);
        min_image(xi, yi, zi, spos[3 * j0 + 576], spos[3 * j0 + 577], spos[3 * j0 + 578], B, Binv, dx3, dy3, dz3, d23);
        unsigned long long m0 = __ballot(d20 < CUT2);
        unsigned long long m1 = __ballot(d21 < CUT2);
        unsigned long long m2 = __ballot(d22 < CUT2);
        unsigned long long m3 = __ballot(d23 < CUT2);
        if (lane == 0) { mrow[c] = m0; mrow[c + 1] = m1; mrow[c + 2] = m2; mrow[c + 3] = m3; }
        cnt += __popcll(m0) + __popcll(m1) + __popcll(m2) + __popcll(m3);
    }
    for (; c < nchunks; ++c) {
        int j = (c << 6) + lane;
        float dx, dy, dz, d2;
        min_image(xi, yi, zi, spos[3 * j + 0], spos[3 * j + 1], spos[3 * j + 2],
                  B, Binv, dx, dy, dz, d2);
        unsigned long long m = __ballot(d2 < CUT2);
        if (lane == 0) mrow[c] = m;
        cnt += __popcll(m);
    }
    return cnt;
}

// K1: pad output + stage positions in LDS + count rows (w, N-1-w) per wave.
__global__ void __launch_bounds__(256)
k1_pad_count(const float* __restrict__ pos, const float* __restrict__ box,
             float* __restrict__ out, int* __restrict__ counts,
             unsigned long long* __restrict__ masks, int N, int P) {
    __shared__ float spos[12288];            // 3*N floats (N=4096) = 48 KB

    int tid = blockIdx.x * blockDim.x + threadIdx.x;
    int nthreads = gridDim.x * blockDim.x;   // (N/2)*64

    // pad: pairs = -1, rest = 0 (stores retire while we compute)
    int total = 6 * P + 1;
    for (int k = tid; k < total; k += nthreads)
        out[k] = (k < 2 * P) ? -1.0f : 0.0f;

    // stage all positions into LDS (coalesced linear copy)
    for (int k = threadIdx.x; k < 3 * N; k += blockDim.x)
        spos[k] = pos[k];
    __syncthreads();

    int w = tid >> 6;
    int lane = tid & 63;
    int nchunks = N >> 6;

    float B[3][3], Binv[3][3];
    load_box_inv(box, B, Binv);

    int rowA = w;            // heavy row (many chunks)
    int rowB = N - 1 - w;    // light row -> balanced total per wave

    int cA = count_row_lds(rowA, lane, spos, B, Binv,
                           masks + (size_t)rowA * nchunks, nchunks);
    if (lane == 0) counts[rowA] = cA;

    int cB = count_row_lds(rowB, lane, spos, B, Binv,
                           masks + (size_t)rowB * nchunks, nchunks);
    if (lane == 0) counts[rowB] = cB;
}

// K2: one wave per row. Inline exclusive prefix over counts[0..i), then
// ordered fill of hits from the precomputed masks.
__global__ void __launch_bounds__(256)
k2_scan_fill(const float* __restrict__ pos, const float* __restrict__ box,
             const int* __restrict__ counts,
             const unsigned long long* __restrict__ masks,
             float* __restrict__ out, int N, int P) {
    int tid = blockIdx.x * blockDim.x + threadIdx.x;
    int i = tid >> 6;
    int lane = tid & 63;
    int nchunks = N >> 6;
    int c0 = i >> 6;

    // Exclusive prefix: sum counts[0..i) across the wave, butterfly-reduce.
    int pre = 0;
    for (int b = 0; b < i; b += 64) {
        int k = b + lane;
        pre += (k < i) ? counts[k] : 0;
    }
    #pragma unroll
    for (int d = 1; d < 64; d <<= 1)
        pre += __shfl_xor(pre, d);           // all lanes: sum(counts[0..i))

    if (i == N - 1 && lane == 0)
        out[6 * (size_t)P] = (float)(pre + counts[i]);   // n_pairs

    // lane l holds the mask of chunk l for this row (only cc >= c0 consumed).
    unsigned long long mymask = masks[(size_t)i * nchunks + lane];

    float B[3][3], Binv[3][3];
    load_box_inv(box, B, Binv);
    float xi = pos[3 * i + 0], yi = pos[3 * i + 1], zi = pos[3 * i + 2];

    int base = pre;
    for (int cc = c0; cc < nchunks; ++cc) {
        unsigned long long m = __shfl(mymask, cc);
        if (m != 0ull) {
            if ((m >> lane) & 1ull) {
                int j = (cc << 6) + lane;
                float dx, dy, dz, d2;
                min_image(xi, yi, zi, pos[3 * j + 0], pos[3 * j + 1], pos[3 * j + 2],
                          B, Binv, dx, dy, dz, d2);
                int slot = base + __popcll(m & ((1ull << lane) - 1ull));
                if (slot < P) {
                    out[slot] = (float)i;                    // pair_i
                    out[P + slot] = (float)j;                // pair_j
                    size_t db = 2 * (size_t)P + 3 * (size_t)slot;
                    out[db + 0] = dx;
                    out[db + 1] = dy;
                    out[db + 2] = dz;
                    out[5 * (size_t)P + slot] = sqrtf(d2);   // distance
                }
            }
            base += __popcll(m);
        }
    }
}

extern "C" void kernel_launch(void* const* d_in, const int* in_sizes, int n_in,
                              void* d_out, int out_size, void* d_ws, size_t ws_size,
                              hipStream_t stream) {
    const float* pos = (const float*)d_in[0];
    const float* box = (const float*)d_in[1];
    float* out = (float*)d_out;

    int N = in_sizes[0] / 3;          // 4096
    int P = (out_size - 1) / 6;       // 131072
    int nchunks = N >> 6;

    // ws layout: counts[N] | masks[N*nchunks]
    char* w = (char*)d_ws;
    int* counts = (int*)w;                         w += (size_t)N * sizeof(int);
    unsigned long long* masks = (unsigned long long*)w;

    // K1: one wave per row-pair -> N/2 waves -> N/8 blocks of 256.
    k1_pad_count<<<N / 8, 256, 0, stream>>>(pos, box, out, counts, masks, N, P);

    // K2: one wave per row -> N/4 blocks of 256.
    k2_scan_fill<<<N / 4, 256, 0, stream>>>(pos, box, counts, masks, out, N, P);
}

// Round 6
// 87.627 us; speedup vs baseline: 1.1787x; 1.1787x over previous
//
#include <hip/hip_runtime.h>

// NeighborList: N atoms, minimum-image convention, cutoff 5.0.
// Output layout (all float32): pairs[2*P], deltas[P*3], distances[P], n_pairs[1]
// Ordering must match jnp.nonzero(mask.ravel()) -> ascending flat index i*N+j.
//
// Two dispatches (cooperative grid.sync measured 100+us on this chip -- avoid;
// LDS staging of positions measured -7.5us regression -- avoid):
//  K1: pad output + per-row count + per-chunk 64-bit hit masks.
//      One wave per row (4096 waves = 4 waves/SIMD occupancy). Diagonal-box
//      fast path: off-diagonal terms are exactly +-0 in numpy too, so
//      dropping them preserves all compared values (only sign-of-zero can
//      differ, which squares/subtracts away).
//  K2: per-wave inline exclusive prefix over counts[] + ordered fill from masks.

#define CUT2 25.0f

__device__ __forceinline__ void load_box_inv(const float* __restrict__ box,
                                             float B[3][3], float Binv[3][3]) {
    #pragma unroll
    for (int r = 0; r < 3; ++r)
        #pragma unroll
        for (int c = 0; c < 3; ++c)
            B[r][c] = box[r * 3 + c];

    float a00 = B[0][0], a01 = B[0][1], a02 = B[0][2];
    float a10 = B[1][0], a11 = B[1][1], a12 = B[1][2];
    float a20 = B[2][0], a21 = B[2][1], a22 = B[2][2];

    float adj00 =  (a11 * a22 - a12 * a21);
    float adj01 = -(a01 * a22 - a02 * a21);
    float adj02 =  (a01 * a12 - a02 * a11);
    float adj10 = -(a10 * a22 - a12 * a20);
    float adj11 =  (a00 * a22 - a02 * a20);
    float adj12 = -(a00 * a12 - a02 * a10);
    float adj20 =  (a10 * a21 - a11 * a20);
    float adj21 = -(a00 * a21 - a01 * a20);
    float adj22 =  (a00 * a11 - a01 * a10);

    float det = a00 * adj00 + a01 * adj10 + a02 * adj20;

    // per-entry division: for diagonal box this rounds identically to
    // LAPACK's 1/pivot (single rounding of the exact quotient).
    Binv[0][0] = __fdiv_rn(adj00, det); Binv[0][1] = __fdiv_rn(adj01, det); Binv[0][2] = __fdiv_rn(adj02, det);
    Binv[1][0] = __fdiv_rn(adj10, det); Binv[1][1] = __fdiv_rn(adj11, det); Binv[1][2] = __fdiv_rn(adj12, det);
    Binv[2][0] = __fdiv_rn(adj20, det); Binv[2][1] = __fdiv_rn(adj21, det); Binv[2][2] = __fdiv_rn(adj22, det);
}

// General triclinic path. Replicates numpy rounding exactly (no FMA):
// delta = pos_i - pos_j; frac = delta @ Binv; delta -= rint(frac) @ B; d2.
__device__ __forceinline__ void min_image(float xi, float yi, float zi,
                                          float xj, float yj, float zj,
                                          const float B[3][3], const float Binv[3][3],
                                          float& dx, float& dy, float& dz, float& d2) {
    dx = __fsub_rn(xi, xj);
    dy = __fsub_rn(yi, yj);
    dz = __fsub_rn(zi, zj);

    float f0 = __fadd_rn(__fadd_rn(__fmul_rn(dx, Binv[0][0]), __fmul_rn(dy, Binv[1][0])), __fmul_rn(dz, Binv[2][0]));
    float f1 = __fadd_rn(__fadd_rn(__fmul_rn(dx, Binv[0][1]), __fmul_rn(dy, Binv[1][1])), __fmul_rn(dz, Binv[2][1]));
    float f2 = __fadd_rn(__fadd_rn(__fmul_rn(dx, Binv[0][2]), __fmul_rn(dy, Binv[1][2])), __fmul_rn(dz, Binv[2][2]));

    float r0 = rintf(f0), r1 = rintf(f1), r2 = rintf(f2);

    float c0 = __fadd_rn(__fadd_rn(__fmul_rn(r0, B[0][0]), __fmul_rn(r1, B[1][0])), __fmul_rn(r2, B[2][0]));
    float c1 = __fadd_rn(__fadd_rn(__fmul_rn(r0, B[0][1]), __fmul_rn(r1, B[1][1])), __fmul_rn(r2, B[2][1]));
    float c2 = __fadd_rn(__fadd_rn(__fmul_rn(r0, B[0][2]), __fmul_rn(r1, B[1][2])), __fmul_rn(r2, B[2][2]));

    dx = __fsub_rn(dx, c0);
    dy = __fsub_rn(dy, c1);
    dz = __fsub_rn(dz, c2);

    d2 = __fadd_rn(__fadd_rn(__fmul_rn(dx, dx), __fmul_rn(dy, dy)), __fmul_rn(dz, dz));
}

// Diagonal-box fast path: same values as the general path when all
// off-diagonal box entries are zero (cross terms are +-0; dropping them can
// only flip sign of an exact zero, which d2 and the wrap subtraction erase).
__device__ __forceinline__ void min_image_diag(float xi, float yi, float zi,
                                               float xj, float yj, float zj,
                                               float b0, float b1, float b2,
                                               float ib0, float ib1, float ib2,
                                               float& dx, float& dy, float& dz, float& d2) {
    dx = __fsub_rn(xi, xj);
    dy = __fsub_rn(yi, yj);
    dz = __fsub_rn(zi, zj);
    float r0 = rintf(__fmul_rn(dx, ib0));
    float r1 = rintf(__fmul_rn(dy, ib1));
    float r2 = rintf(__fmul_rn(dz, ib2));
    dx = __fsub_rn(dx, __fmul_rn(r0, b0));
    dy = __fsub_rn(dy, __fmul_rn(r1, b1));
    dz = __fsub_rn(dz, __fmul_rn(r2, b2));
    d2 = __fadd_rn(__fadd_rn(__fmul_rn(dx, dx), __fmul_rn(dy, dy)), __fmul_rn(dz, dz));
}

// Count hits for row i (j > i); write per-chunk 64-bit masks to mrow[].
template <bool DIAG>
__device__ __forceinline__ int count_row(int i, int lane,
                                         const float* __restrict__ pos,
                                         const float B[3][3], const float Binv[3][3],
                                         unsigned long long* __restrict__ mrow,
                                         int nchunks) {
    float xi = pos[3 * i + 0], yi = pos[3 * i + 1], zi = pos[3 * i + 2];
    float b0 = B[0][0], b1 = B[1][1], b2 = B[2][2];
    float ib0 = Binv[0][0], ib1 = Binv[1][1], ib2 = Binv[2][2];
    int c0 = i >> 6;
    int cnt = 0;

    // Diagonal chunk: needs the j>i predicate.
    {
        int j = (c0 << 6) + lane;
        bool hit = false;
        if (j > i) {
            float dx, dy, dz, d2;
            if (DIAG)
                min_image_diag(xi, yi, zi, pos[3 * j], pos[3 * j + 1], pos[3 * j + 2],
                               b0, b1, b2, ib0, ib1, ib2, dx, dy, dz, d2);
            else
                min_image(xi, yi, zi, pos[3 * j], pos[3 * j + 1], pos[3 * j + 2],
                          B, Binv, dx, dy, dz, d2);
            hit = (d2 < CUT2);
        }
        unsigned long long m = __ballot(hit);
        if (lane == 0) mrow[c0] = m;
        cnt += __popcll(m);
    }

    // Remaining chunks: all j > i. Unroll x4 for ILP.
    int c = c0 + 1;
    for (; c + 4 <= nchunks; c += 4) {
        int j0 = (c << 6) + lane;
        float dx0, dy0, dz0, d20, dx1, dy1, dz1, d21;
        float dx2, dy2, dz2, d22, dx3, dy3, dz3, d23;
        if (DIAG) {
            min_image_diag(xi, yi, zi, pos[3 * j0 +   0], pos[3 * j0 +   1], pos[3 * j0 +   2], b0, b1, b2, ib0, ib1, ib2, dx0, dy0, dz0, d20);
            min_image_diag(xi, yi, zi, pos[3 * j0 + 192], pos[3 * j0 + 193], pos[3 * j0 + 194], b0, b1, b2, ib0, ib1, ib2, dx1, dy1, dz1, d21);
            min_image_diag(xi, yi, zi, pos[3 * j0 + 384], pos[3 * j0 + 385], pos[3 * j0 + 386], b0, b1, b2, ib0, ib1, ib2, dx2, dy2, dz2, d22);
            min_image_diag(xi, yi, zi, pos[3 * j0 + 576], pos[3 * j0 + 577], pos[3 * j0 + 578], b0, b1, b2, ib0, ib1, ib2, dx3, dy3, dz3, d23);
        } else {
            min_image(xi, yi, zi, pos[3 * j0 +   0], pos[3 * j0 +   1], pos[3 * j0 +   2], B, Binv, dx0, dy0, dz0, d20);
            min_image(xi, yi, zi, pos[3 * j0 + 192], pos[3 * j0 + 193], pos[3 * j0 + 194], B, Binv, dx1, dy1, dz1, d21);
            min_image(xi, yi, zi, pos[3 * j0 + 384], pos[3 * j0 + 385], pos[3 * j0 + 386], B, Binv, dx2, dy2, dz2, d22);
            min_image(xi, yi, zi, pos[3 * j0 + 576], pos[3 * j0 + 577], pos[3 * j0 + 578], B, Binv, dx3, dy3, dz3, d23);
        }
        unsigned long long m0 = __ballot(d20 < CUT2);
        unsigned long long m1 = __ballot(d21 < CUT2);
        unsigned long long m2 = __ballot(d22 < CUT2);
        unsigned long long m3 = __ballot(d23 < CUT2);
        if (lane == 0) { mrow[c] = m0; mrow[c + 1] = m1; mrow[c + 2] = m2; mrow[c + 3] = m3; }
        cnt += __popcll(m0) + __popcll(m1) + __popcll(m2) + __popcll(m3);
    }
    for (; c < nchunks; ++c) {
        int j = (c << 6) + lane;
        float dx, dy, dz, d2;
        if (DIAG)
            min_image_diag(xi, yi, zi, pos[3 * j], pos[3 * j + 1], pos[3 * j + 2],
                           b0, b1, b2, ib0, ib1, ib2, dx, dy, dz, d2);
        else
            min_image(xi, yi, zi, pos[3 * j], pos[3 * j + 1], pos[3 * j + 2],
                      B, Binv, dx, dy, dz, d2);
        unsigned long long m = __ballot(d2 < CUT2);
        if (lane == 0) mrow[c] = m;
        cnt += __popcll(m);
    }
    return cnt;
}

// K1: pad output + count one row per wave + write masks.
__global__ void __launch_bounds__(256)
k1_pad_count(const float* __restrict__ pos, const float* __restrict__ box,
             float* __restrict__ out, int* __restrict__ counts,
             unsigned long long* __restrict__ masks, int N, int P) {
    int tid = blockIdx.x * blockDim.x + threadIdx.x;
    int nthreads = gridDim.x * blockDim.x;   // N*64

    // pad: pairs = -1, rest = 0 (stores retire while we compute)
    int total = 6 * P + 1;
    for (int k = tid; k < total; k += nthreads)
        out[k] = (k < 2 * P) ? -1.0f : 0.0f;

    int i = tid >> 6;
    int lane = tid & 63;
    int nchunks = N >> 6;

    float B[3][3], Binv[3][3];
    load_box_inv(box, B, Binv);
    bool diag = (B[0][1] == 0.0f) & (B[0][2] == 0.0f) & (B[1][0] == 0.0f) &
                (B[1][2] == 0.0f) & (B[2][0] == 0.0f) & (B[2][1] == 0.0f);

    int cnt;
    if (diag)
        cnt = count_row<true>(i, lane, pos, B, Binv,
                              masks + (size_t)i * nchunks, nchunks);
    else
        cnt = count_row<false>(i, lane, pos, B, Binv,
                               masks + (size_t)i * nchunks, nchunks);
    if (lane == 0) counts[i] = cnt;
}

// K2: one wave per row. Inline exclusive prefix over counts[0..i), then
// ordered fill of hits from the precomputed masks (general math path:
// only ~n_pairs re-evals, value-identical to numpy).
__global__ void __launch_bounds__(256)
k2_scan_fill(const float* __restrict__ pos, const float* __restrict__ box,
             const int* __restrict__ counts,
             const unsigned long long* __restrict__ masks,
             float* __restrict__ out, int N, int P) {
    int tid = blockIdx.x * blockDim.x + threadIdx.x;
    int i = tid >> 6;
    int lane = tid & 63;
    int nchunks = N >> 6;
    int c0 = i >> 6;

    // Exclusive prefix: sum counts[0..i) across the wave, butterfly-reduce.
    int pre = 0;
    for (int b = 0; b < i; b += 64) {
        int k = b + lane;
        pre += (k < i) ? counts[k] : 0;
    }
    #pragma unroll
    for (int d = 1; d < 64; d <<= 1)
        pre += __shfl_xor(pre, d);           // all lanes: sum(counts[0..i))

    if (i == N - 1 && lane == 0)
        out[6 * (size_t)P] = (float)(pre + counts[i]);   // n_pairs

    // lane l holds the mask of chunk l for this row (only cc >= c0 consumed).
    unsigned long long mymask = masks[(size_t)i * nchunks + lane];

    float B[3][3], Binv[3][3];
    load_box_inv(box, B, Binv);
    float xi = pos[3 * i + 0], yi = pos[3 * i + 1], zi = pos[3 * i + 2];

    int base = pre;
    for (int cc = c0; cc < nchunks; ++cc) {
        unsigned long long m = __shfl(mymask, cc);
        if (m != 0ull) {
            if ((m >> lane) & 1ull) {
                int j = (cc << 6) + lane;
                float dx, dy, dz, d2;
                min_image(xi, yi, zi, pos[3 * j + 0], pos[3 * j + 1], pos[3 * j + 2],
                          B, Binv, dx, dy, dz, d2);
                int slot = base + __popcll(m & ((1ull << lane) - 1ull));
                if (slot < P) {
                    out[slot] = (float)i;                    // pair_i
                    out[P + slot] = (float)j;                // pair_j
                    size_t db = 2 * (size_t)P + 3 * (size_t)slot;
                    out[db + 0] = dx;
                    out[db + 1] = dy;
                    out[db + 2] = dz;
                    out[5 * (size_t)P + slot] = sqrtf(d2);   // distance
                }
            }
            base += __popcll(m);
        }
    }
}

extern "C" void kernel_launch(void* const* d_in, const int* in_sizes, int n_in,
                              void* d_out, int out_size, void* d_ws, size_t ws_size,
                              hipStream_t stream) {
    const float* pos = (const float*)d_in[0];
    const float* box = (const float*)d_in[1];
    float* out = (float*)d_out;

    int N = in_sizes[0] / 3;          // 4096
    int P = (out_size - 1) / 6;       // 131072
    int nchunks = N >> 6;

    // ws layout: counts[N] | masks[N*nchunks]
    char* w = (char*)d_ws;
    int* counts = (int*)w;                         w += (size_t)N * sizeof(int);
    unsigned long long* masks = (unsigned long long*)w;

    // K1: one wave per row -> N waves -> N/4 blocks of 256 (4 waves/SIMD).
    k1_pad_count<<<N / 4, 256, 0, stream>>>(pos, box, out, counts, masks, N, P);

    // K2: one wave per row -> N/4 blocks of 256.
    k2_scan_fill<<<N / 4, 256, 0, stream>>>(pos, box, counts, masks, out, N, P);
}

// Round 7
// 87.603 us; speedup vs baseline: 1.1790x; 1.0003x over previous
//
#include <hip/hip_runtime.h>

// NeighborList: N atoms, minimum-image convention, cutoff 5.0.
// Output layout (all float32): pairs[2*P], deltas[P*3], distances[P], n_pairs[1]
// Ordering must match jnp.nonzero(mask.ravel()) -> ascending flat index i*N+j.
//
// Two dispatches (cooperative grid.sync measured 100+us -- avoid; LDS staging
// measured -7.5us -- avoid). Half-row decomposition: wave = (row, half) ->
// 8192 waves = 32 waves/CU (was 16). Block b holds both halves of rows
// {b, N-1-b} -> ~65 chunk-iters per block (balanced makespan).
//  K1: pad output + per-half-row count + per-chunk 64-bit hit masks.
//  K2: per-wave int4 prefix over counts2[] + ordered fill from masks
//      (half B base = prefix + countA -- ordering preserved by construction).

#define CUT2 25.0f

__device__ __forceinline__ void load_box_inv(const float* __restrict__ box,
                                             float B[3][3], float Binv[3][3]) {
    #pragma unroll
    for (int r = 0; r < 3; ++r)
        #pragma unroll
        for (int c = 0; c < 3; ++c)
            B[r][c] = box[r * 3 + c];

    float a00 = B[0][0], a01 = B[0][1], a02 = B[0][2];
    float a10 = B[1][0], a11 = B[1][1], a12 = B[1][2];
    float a20 = B[2][0], a21 = B[2][1], a22 = B[2][2];

    float adj00 =  (a11 * a22 - a12 * a21);
    float adj01 = -(a01 * a22 - a02 * a21);
    float adj02 =  (a01 * a12 - a02 * a11);
    float adj10 = -(a10 * a22 - a12 * a20);
    float adj11 =  (a00 * a22 - a02 * a20);
    float adj12 = -(a00 * a12 - a02 * a10);
    float adj20 =  (a10 * a21 - a11 * a20);
    float adj21 = -(a00 * a21 - a01 * a20);
    float adj22 =  (a00 * a11 - a01 * a10);

    float det = a00 * adj00 + a01 * adj10 + a02 * adj20;

    // per-entry division: for diagonal box this rounds identically to
    // LAPACK's 1/pivot (single rounding of the exact quotient).
    Binv[0][0] = __fdiv_rn(adj00, det); Binv[0][1] = __fdiv_rn(adj01, det); Binv[0][2] = __fdiv_rn(adj02, det);
    Binv[1][0] = __fdiv_rn(adj10, det); Binv[1][1] = __fdiv_rn(adj11, det); Binv[1][2] = __fdiv_rn(adj12, det);
    Binv[2][0] = __fdiv_rn(adj20, det); Binv[2][1] = __fdiv_rn(adj21, det); Binv[2][2] = __fdiv_rn(adj22, det);
}

// General triclinic path. Replicates numpy rounding exactly (no FMA):
// delta = pos_i - pos_j; frac = delta @ Binv; delta -= rint(frac) @ B; d2.
__device__ __forceinline__ void min_image(float xi, float yi, float zi,
                                          float xj, float yj, float zj,
                                          const float B[3][3], const float Binv[3][3],
                                          float& dx, float& dy, float& dz, float& d2) {
    dx = __fsub_rn(xi, xj);
    dy = __fsub_rn(yi, yj);
    dz = __fsub_rn(zi, zj);

    float f0 = __fadd_rn(__fadd_rn(__fmul_rn(dx, Binv[0][0]), __fmul_rn(dy, Binv[1][0])), __fmul_rn(dz, Binv[2][0]));
    float f1 = __fadd_rn(__fadd_rn(__fmul_rn(dx, Binv[0][1]), __fmul_rn(dy, Binv[1][1])), __fmul_rn(dz, Binv[2][1]));
    float f2 = __fadd_rn(__fadd_rn(__fmul_rn(dx, Binv[0][2]), __fmul_rn(dy, Binv[1][2])), __fmul_rn(dz, Binv[2][2]));

    float r0 = rintf(f0), r1 = rintf(f1), r2 = rintf(f2);

    float c0 = __fadd_rn(__fadd_rn(__fmul_rn(r0, B[0][0]), __fmul_rn(r1, B[1][0])), __fmul_rn(r2, B[2][0]));
    float c1 = __fadd_rn(__fadd_rn(__fmul_rn(r0, B[0][1]), __fmul_rn(r1, B[1][1])), __fmul_rn(r2, B[2][1]));
    float c2 = __fadd_rn(__fadd_rn(__fmul_rn(r0, B[0][2]), __fmul_rn(r1, B[1][2])), __fmul_rn(r2, B[2][2]));

    dx = __fsub_rn(dx, c0);
    dy = __fsub_rn(dy, c1);
    dz = __fsub_rn(dz, c2);

    d2 = __fadd_rn(__fadd_rn(__fmul_rn(dx, dx), __fmul_rn(dy, dy)), __fmul_rn(dz, dz));
}

// Diagonal-box fast path: same values as the general path when all
// off-diagonal box entries are zero (cross terms are +-0; dropping them can
// only flip sign of an exact zero, which d2 and the wrap subtraction erase).
__device__ __forceinline__ void min_image_diag(float xi, float yi, float zi,
                                               float xj, float yj, float zj,
                                               float b0, float b1, float b2,
                                               float ib0, float ib1, float ib2,
                                               float& dx, float& dy, float& dz, float& d2) {
    dx = __fsub_rn(xi, xj);
    dy = __fsub_rn(yi, yj);
    dz = __fsub_rn(zi, zj);
    float r0 = rintf(__fmul_rn(dx, ib0));
    float r1 = rintf(__fmul_rn(dy, ib1));
    float r2 = rintf(__fmul_rn(dz, ib2));
    dx = __fsub_rn(dx, __fmul_rn(r0, b0));
    dy = __fsub_rn(dy, __fmul_rn(r1, b1));
    dz = __fsub_rn(dz, __fmul_rn(r2, b2));
    d2 = __fadd_rn(__fadd_rn(__fmul_rn(dx, dx), __fmul_rn(dy, dy)), __fmul_rn(dz, dz));
}

// Wave -> (row, half) mapping shared by K1/K2. Block b holds both halves of
// rows b and N-1-b (heavy+light -> balanced block work).
__device__ __forceinline__ void wave_row_half(int w, int N, int& row, int& h) {
    h = w & 1;
    int rp = w >> 1;                 // 0..N-1
    row = (rp & 1) ? (N - 1 - (rp >> 1)) : (rp >> 1);
}

// Chunk range [start,end) for (row, half).
__device__ __forceinline__ void half_range(int row, int h, int nchunks,
                                           int& start, int& end, int& c0) {
    c0 = row >> 6;
    int nc = nchunks - c0;
    int midc = c0 + ((nc + 1) >> 1);   // half A gets the ceil (incl. diag chunk)
    start = h ? midc : c0;
    end = h ? nchunks : midc;
}

// Count hits for row i over chunks [start,end); write per-chunk masks.
// DIAG selects the diagonal-box fast path.
template <bool DIAG>
__device__ __forceinline__ int count_half(int i, int lane, int start, int end, int c0,
                                          const float* __restrict__ pos,
                                          const float B[3][3], const float Binv[3][3],
                                          unsigned long long* __restrict__ mrow) {
    float xi = pos[3 * i + 0], yi = pos[3 * i + 1], zi = pos[3 * i + 2];
    float b0 = B[0][0], b1 = B[1][1], b2 = B[2][2];
    float ib0 = Binv[0][0], ib1 = Binv[1][1], ib2 = Binv[2][2];
    int cnt = 0;
    int c = start;

    // Diagonal chunk (only ever in half A): needs the j>i predicate.
    if (c == c0 && c < end) {
        int j = (c0 << 6) + lane;
        bool hit = false;
        if (j > i) {
            float dx, dy, dz, d2;
            if (DIAG)
                min_image_diag(xi, yi, zi, pos[3 * j], pos[3 * j + 1], pos[3 * j + 2],
                               b0, b1, b2, ib0, ib1, ib2, dx, dy, dz, d2);
            else
                min_image(xi, yi, zi, pos[3 * j], pos[3 * j + 1], pos[3 * j + 2],
                          B, Binv, dx, dy, dz, d2);
            hit = (d2 < CUT2);
        }
        unsigned long long m = __ballot(hit);
        if (lane == 0) mrow[c0] = m;
        cnt += __popcll(m);
        ++c;
    }

    // Remaining chunks: all j > i. Unroll x4 for ILP.
    for (; c + 4 <= end; c += 4) {
        int j0 = (c << 6) + lane;
        float dx0, dy0, dz0, d20, dx1, dy1, dz1, d21;
        float dx2, dy2, dz2, d22, dx3, dy3, dz3, d23;
        if (DIAG) {
            min_image_diag(xi, yi, zi, pos[3 * j0 +   0], pos[3 * j0 +   1], pos[3 * j0 +   2], b0, b1, b2, ib0, ib1, ib2, dx0, dy0, dz0, d20);
            min_image_diag(xi, yi, zi, pos[3 * j0 + 192], pos[3 * j0 + 193], pos[3 * j0 + 194], b0, b1, b2, ib0, ib1, ib2, dx1, dy1, dz1, d21);
            min_image_diag(xi, yi, zi, pos[3 * j0 + 384], pos[3 * j0 + 385], pos[3 * j0 + 386], b0, b1, b2, ib0, ib1, ib2, dx2, dy2, dz2, d22);
            min_image_diag(xi, yi, zi, pos[3 * j0 + 576], pos[3 * j0 + 577], pos[3 * j0 + 578], b0, b1, b2, ib0, ib1, ib2, dx3, dy3, dz3, d23);
        } else {
            min_image(xi, yi, zi, pos[3 * j0 +   0], pos[3 * j0 +   1], pos[3 * j0 +   2], B, Binv, dx0, dy0, dz0, d20);
            min_image(xi, yi, zi, pos[3 * j0 + 192], pos[3 * j0 + 193], pos[3 * j0 + 194], B, Binv, dx1, dy1, dz1, d21);
            min_image(xi, yi, zi, pos[3 * j0 + 384], pos[3 * j0 + 385], pos[3 * j0 + 386], B, Binv, dx2, dy2, dz2, d22);
            min_image(xi, yi, zi, pos[3 * j0 + 576], pos[3 * j0 + 577], pos[3 * j0 + 578], B, Binv, dx3, dy3, dz3, d23);
        }
        unsigned long long m0 = __ballot(d20 < CUT2);
        unsigned long long m1 = __ballot(d21 < CUT2);
        unsigned long long m2 = __ballot(d22 < CUT2);
        unsigned long long m3 = __ballot(d23 < CUT2);
        if (lane == 0) { mrow[c] = m0; mrow[c + 1] = m1; mrow[c + 2] = m2; mrow[c + 3] = m3; }
        cnt += __popcll(m0) + __popcll(m1) + __popcll(m2) + __popcll(m3);
    }
    for (; c < end; ++c) {
        int j = (c << 6) + lane;
        float dx, dy, dz, d2;
        if (DIAG)
            min_image_diag(xi, yi, zi, pos[3 * j], pos[3 * j + 1], pos[3 * j + 2],
                           b0, b1, b2, ib0, ib1, ib2, dx, dy, dz, d2);
        else
            min_image(xi, yi, zi, pos[3 * j], pos[3 * j + 1], pos[3 * j + 2],
                      B, Binv, dx, dy, dz, d2);
        unsigned long long m = __ballot(d2 < CUT2);
        if (lane == 0) mrow[c] = m;
        cnt += __popcll(m);
    }
    return cnt;
}

// K1: pad output + count one (row, half) per wave + write masks.
__global__ void __launch_bounds__(256)
k1_pad_count(const float* __restrict__ pos, const float* __restrict__ box,
             float* __restrict__ out, int* __restrict__ counts2,
             unsigned long long* __restrict__ masks, int N, int P) {
    int tid = blockIdx.x * blockDim.x + threadIdx.x;
    int nthreads = gridDim.x * blockDim.x;   // 2N*64

    // pad: pairs = -1, rest = 0 (stores retire while we compute)
    int total = 6 * P + 1;
    for (int k = tid; k < total; k += nthreads)
        out[k] = (k < 2 * P) ? -1.0f : 0.0f;

    int w = tid >> 6;
    int lane = tid & 63;
    int nchunks = N >> 6;

    int row, h;
    wave_row_half(w, N, row, h);
    int start, end, c0;
    half_range(row, h, nchunks, start, end, c0);

    float B[3][3], Binv[3][3];
    load_box_inv(box, B, Binv);
    bool diag = (B[0][1] == 0.0f) & (B[0][2] == 0.0f) & (B[1][0] == 0.0f) &
                (B[1][2] == 0.0f) & (B[2][0] == 0.0f) & (B[2][1] == 0.0f);

    unsigned long long* mrow = masks + (size_t)row * nchunks;
    int cnt;
    if (diag)
        cnt = count_half<true>(row, lane, start, end, c0, pos, B, Binv, mrow);
    else
        cnt = count_half<false>(row, lane, start, end, c0, pos, B, Binv, mrow);
    if (lane == 0) counts2[2 * row + h] = cnt;
}

// K2: one (row, half) per wave. int4 prefix over counts2[0..2*row), half B
// adds countA; then ordered fill of this half's chunks from the masks.
__global__ void __launch_bounds__(256)
k2_scan_fill(const float* __restrict__ pos, const float* __restrict__ box,
             const int* __restrict__ counts2,
             const unsigned long long* __restrict__ masks,
             float* __restrict__ out, int N, int P) {
    int tid = blockIdx.x * blockDim.x + threadIdx.x;
    int w = tid >> 6;
    int lane = tid & 63;
    int nchunks = N >> 6;

    int row, h;
    wave_row_half(w, N, row, h);
    int start, end, c0;
    half_range(row, h, nchunks, start, end, c0);

    // Exclusive prefix over counts2[0..2*row) via int4 loads + butterfly.
    int lim = 2 * row;
    int pre = 0;
    for (int base = 0; base < lim; base += 256) {
        int idx = base + 4 * lane;
        int4 v = *(const int4*)(counts2 + idx);   // may read past lim; masked below
        if (idx + 0 < lim) pre += v.x;
        if (idx + 1 < lim) pre += v.y;
        if (idx + 2 < lim) pre += v.z;
        if (idx + 3 < lim) pre += v.w;
    }
    #pragma unroll
    for (int d = 1; d < 64; d <<= 1)
        pre += __shfl_xor(pre, d);               // all lanes: sum counts2[0..2*row)

    if (h == 1) pre += counts2[2 * row];         // half B starts after half A

    if (row == N - 1 && h == 1 && lane == 0)
        out[6 * (size_t)P] = (float)(pre + counts2[2 * row + 1]);   // n_pairs

    // lane l holds the mask of chunk l for this row.
    unsigned long long mymask = masks[(size_t)row * nchunks + lane];

    float B[3][3], Binv[3][3];
    load_box_inv(box, B, Binv);
    float xi = pos[3 * row + 0], yi = pos[3 * row + 1], zi = pos[3 * row + 2];

    int base = pre;
    for (int cc = start; cc < end; ++cc) {
        unsigned long long m = __shfl(mymask, cc);
        if (m != 0ull) {
            if ((m >> lane) & 1ull) {
                int j = (cc << 6) + lane;
                float dx, dy, dz, d2;
                min_image(xi, yi, zi, pos[3 * j + 0], pos[3 * j + 1], pos[3 * j + 2],
                          B, Binv, dx, dy, dz, d2);
                int slot = base + __popcll(m & ((1ull << lane) - 1ull));
                if (slot < P) {
                    out[slot] = (float)row;                  // pair_i
                    out[P + slot] = (float)j;                // pair_j
                    size_t db = 2 * (size_t)P + 3 * (size_t)slot;
                    out[db + 0] = dx;
                    out[db + 1] = dy;
                    out[db + 2] = dz;
                    out[5 * (size_t)P + slot] = sqrtf(d2);   // distance
                }
            }
            base += __popcll(m);
        }
    }
}

extern "C" void kernel_launch(void* const* d_in, const int* in_sizes, int n_in,
                              void* d_out, int out_size, void* d_ws, size_t ws_size,
                              hipStream_t stream) {
    const float* pos = (const float*)d_in[0];
    const float* box = (const float*)d_in[1];
    float* out = (float*)d_out;

    int N = in_sizes[0] / 3;          // 4096
    int P = (out_size - 1) / 6;       // 131072
    int nchunks = N >> 6;

    // ws layout: counts2[2N] | masks[N*nchunks]
    char* w = (char*)d_ws;
    int* counts2 = (int*)w;                        w += (size_t)2 * N * sizeof(int);
    unsigned long long* masks = (unsigned long long*)w;

    // 2 waves per row (halves) -> 2N waves -> N/2 blocks of 256 (32 waves/CU).
    k1_pad_count<<<N / 2, 256, 0, stream>>>(pos, box, out, counts2, masks, N, P);
    k2_scan_fill<<<N / 2, 256, 0, stream>>>(pos, box, counts2, masks, out, N, P);
}